// Round 3
// baseline (241.099 us; speedup 1.0000x reference)
//
#include <hip/hip_runtime.h>

// ALiBi bias subtraction: out[b,h,i,j] = scores[b,h,i,j] - slope(h)*(i-j)
// (offset cancels in pos_diff). B=2, H=16, S=2048 -> shift/mask index decomp.
// Streaming, memory-bound. v3: native clang vector type (ext_vector_type) so
// __builtin_nontemporal_load/store compile; 4x-unrolled grid-stride with 4
// independent nontemporal loads in flight per iteration (MLP).

typedef float f32x4 __attribute__((ext_vector_type(4)));

__device__ __forceinline__ f32x4 alibi_apply(f32x4 s, unsigned int idx4) {
    const unsigned int e = idx4 << 2;              // element index of lane's .x
    const int j = (int)(e & 2047u);                // S = 2048
    const int i = (int)((e >> 11) & 2047u);
    const int h = (int)((e >> 22) & 15u);          // H = 16
    const float slope = exp2f(-0.5f * (float)(h + 1));  // 2^(-8*(h+1)/16)
    const int d = i - j;
    f32x4 o;
    o.x = s.x - slope * (float)(d);
    o.y = s.y - slope * (float)(d - 1);
    o.z = s.z - slope * (float)(d - 2);
    o.w = s.w - slope * (float)(d - 3);
    return o;
}

__global__ __launch_bounds__(256) void alibi_kernel(const f32x4* __restrict__ in,
                                                    f32x4* __restrict__ out,
                                                    unsigned int n4) {
    const unsigned int stride = gridDim.x * blockDim.x;
    unsigned int idx = blockIdx.x * blockDim.x + threadIdx.x;

    // Main loop: 4 independent loads in flight before any compute/store.
    for (; idx + 3u * stride < n4; idx += 4u * stride) {
        const unsigned int i0 = idx;
        const unsigned int i1 = idx + stride;
        const unsigned int i2 = idx + 2u * stride;
        const unsigned int i3 = idx + 3u * stride;
        f32x4 s0 = __builtin_nontemporal_load(&in[i0]);
        f32x4 s1 = __builtin_nontemporal_load(&in[i1]);
        f32x4 s2 = __builtin_nontemporal_load(&in[i2]);
        f32x4 s3 = __builtin_nontemporal_load(&in[i3]);
        f32x4 o0 = alibi_apply(s0, i0);
        f32x4 o1 = alibi_apply(s1, i1);
        f32x4 o2 = alibi_apply(s2, i2);
        f32x4 o3 = alibi_apply(s3, i3);
        __builtin_nontemporal_store(o0, &out[i0]);
        __builtin_nontemporal_store(o1, &out[i1]);
        __builtin_nontemporal_store(o2, &out[i2]);
        __builtin_nontemporal_store(o3, &out[i3]);
    }
    // Tail (never taken for the bench shape: n4 % (4*stride) == 0).
    for (; idx < n4; idx += stride) {
        f32x4 s = __builtin_nontemporal_load(&in[idx]);
        __builtin_nontemporal_store(alibi_apply(s, idx), &out[idx]);
    }
}

extern "C" void kernel_launch(void* const* d_in, const int* in_sizes, int n_in,
                              void* d_out, int out_size, void* d_ws, size_t ws_size,
                              hipStream_t stream) {
    const f32x4* in = (const f32x4*)d_in[0];
    f32x4* out = (f32x4*)d_out;
    const unsigned int n4 = (unsigned int)(out_size / 4);  // 33554432 float4s
    const int block = 256;
    const int grid = 2048;  // 8 blocks/CU * 256 CUs; 64 iters/thread -> 16 unrolled
    alibi_kernel<<<grid, block, 0, stream>>>(in, out, n4);
}